// Round 6
// baseline (1457.995 us; speedup 1.0000x reference)
//
#include <hip/hip_runtime.h>

#define Vn 128
#define En 32
#define Hn 128
#define Bn 4
#define Sn 512
#define G4H 512   // 4*Hn

__device__ __forceinline__ float fsigmoid(float x) {
    return 1.0f / (1.0f + __expf(-x));
}

__device__ __forceinline__ float ftanh(float x) {
    float ax = fabsf(x);
    float e  = __expf(2.0f * ax);
    float t  = 1.0f - 2.0f / (e + 1.0f);
    return copysignf(t, x);
}

// Sum across the 4 lanes of each aligned lane-quad via DPP quad_perm
// (VALU pipe — no LDS traffic, no barrier). 0xB1 = xor1, 0x4E = xor2.
__device__ __forceinline__ float quad_sum(float v) {
    v += __int_as_float(__builtin_amdgcn_update_dpp(
            0, __float_as_int(v), 0xB1, 0xF, 0xF, true));
    v += __int_as_float(__builtin_amdgcn_update_dpp(
            0, __float_as_int(v), 0x4E, 0xF, 0xF, true));
    return v;
}

// ---------------------------------------------------------------------------
// Kernel A: Gtab[v][j][g] = (b_ih+b_hh)[g*128+j] + emb[v]·W_ih[g*128+j]
// Interleaved gate layout so k_lstm's bias load is a single b128.
// ---------------------------------------------------------------------------
__global__ __launch_bounds__(512) void k_gtab(
        const float* __restrict__ emb, const float* __restrict__ Wih,
        const float* __restrict__ bih, const float* __restrict__ bhh,
        float* __restrict__ Gtab) {
    int v  = blockIdx.x;
    int t  = threadIdx.x;
    int j  = t >> 2;
    int gt = t & 3;
    int r  = gt * Hn + j;   // gate row in (i,f,g,o) order
    __shared__ float e[En];
    if (t < En) e[t] = emb[v * En + t];
    __syncthreads();
    const float4* wr = (const float4*)(Wih + r * En);
    float acc = bih[r] + bhh[r];
#pragma unroll
    for (int i = 0; i < En / 4; i++) {
        float4 w4 = wr[i];
        acc += w4.x * e[4*i] + w4.y * e[4*i+1] + w4.z * e[4*i+2] + w4.w * e[4*i+3];
    }
    Gtab[v * G4H + t] = acc;   // [v][j][gt]
}

// ---------------------------------------------------------------------------
// Kernel B: LSTM recurrence. One block per batch (4 CUs), 1024 threads.
// tid = 8*j + q: 8 lanes per hidden row j, each owning a 16-wide K-slice of
// all four gate rows -> only 64 weight floats/thread (16 float4 = 64 VGPRs),
// small enough for the allocator to keep resident at 4 waves/SIMD
// (R1-R5 post-mortem: the 512-thread/128-float layout never became
// register-resident -> 256KB/step L1 re-stream == the ~2000 cyc/step wall).
// Reduction: DPP quad butterfly + shfl_xor(4); gate sums via LDS; activations
// and (c,h) state on threads<128 only (waves 2..15 skip at zero issue cost).
// ---------------------------------------------------------------------------
__global__ __attribute__((amdgpu_flat_work_group_size(1024, 1024),
                          amdgpu_waves_per_eu(4, 4)))
void k_lstm(
        const float* __restrict__ Whh, const float* __restrict__ Gtab,
        const int* __restrict__ x,
        float* __restrict__ out, float* __restrict__ hT, float* __restrict__ cT) {
    int b   = blockIdx.x;
    int tid = threadIdx.x;
    int q   = tid & 7;        // K-slice [16q, 16q+16)
    int j   = tid >> 3;       // hidden row 0..127

    __shared__ float hbuf[2][144];        // 8 slices x 18-dword stride
    __shared__ float gsum[4][132];        // per-gate row sums (+pad)
    __shared__ float hstage[2][8][Hn];    // double-buffered octet stage
    __shared__ int   xb[Sn];

    if (tid < Sn) xb[tid] = x[b * Sn + tid];
    if (tid < 288) ((float*)hbuf)[tid] = 0.0f;

    // per-thread weights: rows {g*128+j}, cols [16q,16q+16) -> 16 float4
    float4 w[4][4];
#pragma unroll
    for (int g = 0; g < 4; g++) {
        const float4* row = (const float4*)(Whh + (g * Hn + j) * Hn + q * 16);
#pragma unroll
        for (int i = 0; i < 4; i++) w[g][i] = row[i];
    }

    float c = 0.0f, h = 0.0f;
    __syncthreads();

    float* out_base = out + b * Sn * Hn;

    for (int s = 0; s < Sn; s++) {
        // keep w opaque each iteration (belt+suspenders vs remat)
#pragma unroll
        for (int g = 0; g < 4; g++) {
#pragma unroll
            for (int i = 0; i < 4; i++) {
                asm volatile("" : "+v"(w[g][i].x), "+v"(w[g][i].y),
                                  "+v"(w[g][i].z), "+v"(w[g][i].w));
            }
        }
        // prefetch this step's gate bias (consumed in phase B after barrier)
        float4 gx = {0.f, 0.f, 0.f, 0.f};
        if (tid < Hn) gx = *(const float4*)(Gtab + xb[s] * G4H + tid * 4);

        // h_{s-1} slice for this lane (slices at stride 18 -> <=2-way banks)
        const float4* hp = (const float4*)(hbuf[(s + 1) & 1] + 18 * q);
        float4 hv[4];
#pragma unroll
        for (int i = 0; i < 4; i++) hv[i] = hp[i];

        float p0 = 0.f, p1 = 0.f, p2 = 0.f, p3 = 0.f;
#pragma unroll
        for (int i = 0; i < 4; i++) {
            p0 += w[0][i].x * hv[i].x + w[0][i].y * hv[i].y
                + w[0][i].z * hv[i].z + w[0][i].w * hv[i].w;
            p1 += w[1][i].x * hv[i].x + w[1][i].y * hv[i].y
                + w[1][i].z * hv[i].z + w[1][i].w * hv[i].w;
            p2 += w[2][i].x * hv[i].x + w[2][i].y * hv[i].y
                + w[2][i].z * hv[i].z + w[2][i].w * hv[i].w;
            p3 += w[3][i].x * hv[i].x + w[3][i].y * hv[i].y
                + w[3][i].z * hv[i].z + w[3][i].w * hv[i].w;
        }
        // 8-lane all-reduce: quads via DPP, cross-quad via shfl_xor(4)
        p0 = quad_sum(p0); p0 += __shfl_xor(p0, 4);
        p1 = quad_sum(p1); p1 += __shfl_xor(p1, 4);
        p2 = quad_sum(p2); p2 += __shfl_xor(p2, 4);
        p3 = quad_sum(p3); p3 += __shfl_xor(p3, 4);

        if (q == 0) {   // 8 consecutive-j lanes per wave -> conflict-free
            gsum[0][j] = p0;
            gsum[1][j] = p1;
            gsum[2][j] = p2;
            gsum[3][j] = p3;
        }
        __syncthreads();

        if (tid < Hn) {   // waves 0,1 only; waves 2..15 skip at no cost
            float gi = gx.x + gsum[0][tid];
            float gf = gx.y + gsum[1][tid];
            float gg = gx.z + gsum[2][tid];
            float go = gx.w + gsum[3][tid];
            c = fsigmoid(gf) * c + fsigmoid(gi) * ftanh(gg);
            h = fsigmoid(go) * ftanh(c);
            hbuf[s & 1][18 * (tid >> 4) + (tid & 15)] = h;
            hstage[(s >> 3) & 1][s & 7][tid] = h;
        }
        __syncthreads();

        if ((s & 7) == 7) {   // flush 8 steps of h, 1 coalesced b32/thread
            int row = tid >> 7;
            int col = tid & 127;
            out_base[(s - 7 + row) * Hn + col] = hstage[(s >> 3) & 1][row][col];
        }
    }
    if (tid < Hn) {
        hT[b * Hn + tid] = h;
        cT[b * Hn + tid] = c;
    }
}

// ---------------------------------------------------------------------------
// Kernel C: q = out@Wq.T + bq ; k = out@Wk.T + bk
// ---------------------------------------------------------------------------
__global__ __launch_bounds__(256) void k_qk(
        const float* __restrict__ out, const float* __restrict__ Wq,
        const float* __restrict__ bq, const float* __restrict__ Wk,
        const float* __restrict__ bk, float* __restrict__ qo, float* __restrict__ ko) {
    int bs  = blockIdx.x;
    int tid = threadIdx.x;
    __shared__ float o[Hn];
    if (tid < Hn) o[tid] = out[bs * Hn + tid];
    __syncthreads();
    int h = tid & 127;
    const float* Wm = (tid < Hn) ? Wq : Wk;
    const float* bm = (tid < Hn) ? bq : bk;
    const float4* wr = (const float4*)(Wm + h * Hn);
    float acc = bm[h];
#pragma unroll
    for (int i = 0; i < Hn / 4; i++) {
        float4 w4 = wr[i];
        acc += w4.x * o[4*i] + w4.y * o[4*i+1] + w4.z * o[4*i+2] + w4.w * o[4*i+3];
    }
    float* dst = (tid < Hn) ? qo : ko;
    dst[bs * Hn + h] = acc;
}

// ---------------------------------------------------------------------------
// Kernel D: Bahdanau scores + causal softmax + ctx + FINAL PROJECTION fused.
// Block per (b,t), 512 threads. ctx never leaves LDS.
// ---------------------------------------------------------------------------
__global__ __launch_bounds__(512) void k_attn(
        const float* __restrict__ qo, const float* __restrict__ ko,
        const float* __restrict__ vvec, const float* __restrict__ out,
        const float* __restrict__ Wf, const float* __restrict__ bf,
        float* __restrict__ logits) {
    int b   = blockIdx.x >> 9;
    int t   = blockIdx.x & (Sn - 1);
    int tid = threadIdx.x;
    int ln  = tid & 63;
    int wv  = tid >> 6;
    __shared__ float qs[Hn];
    __shared__ float vs[Hn];
    __shared__ float os[Hn];       // out[t]
    __shared__ float sc[Sn];
    __shared__ float redm[8];
    __shared__ float reds[8];
    __shared__ float part[16][Hn];
    __shared__ float oc[2 * Hn];   // [out[t], ctx]

    if (tid < Hn) {
        qs[tid] = qo[(b * Sn + t) * Hn + tid];
        vs[tid] = vvec[tid];
        os[tid] = out[(b * Sn + t) * Hn + tid];
    }
    __syncthreads();

    // --- score for key index i = tid (if <= t) ---
    float sval = 0.0f;
    float a = -1e30f;
    if (tid <= t) {
        const float4* kr = (const float4*)(ko + (b * Sn + tid) * Hn);
        float s = 0.0f;
#pragma unroll
        for (int u = 0; u < Hn / 4; u++) {
            float4 k4 = kr[u];
            s += vs[4*u]   * ftanh(qs[4*u]   + k4.x);
            s += vs[4*u+1] * ftanh(qs[4*u+1] + k4.y);
            s += vs[4*u+2] * ftanh(qs[4*u+2] + k4.z);
            s += vs[4*u+3] * ftanh(qs[4*u+3] + k4.w);
        }
        sval = s;
        a = s;
    }
#pragma unroll
    for (int off = 32; off >= 1; off >>= 1)
        a = fmaxf(a, __shfl_xor(a, off));
    if (ln == 0) redm[wv] = a;
    __syncthreads();
    float m = redm[0];
#pragma unroll
    for (int r = 1; r < 8; r++) m = fmaxf(m, redm[r]);

    float ev = 0.0f;
    if (tid <= t) {
        ev = __expf(sval - m);
        sc[tid] = ev;
    }
    float ssum = ev;
#pragma unroll
    for (int off = 32; off >= 1; off >>= 1)
        ssum += __shfl_xor(ssum, off);
    if (ln == 0) reds[wv] = ssum;
    __syncthreads();
    float tot = 0.0f;
#pragma unroll
    for (int r = 0; r < 8; r++) tot += reds[r];
    float inv = 1.0f / tot;

    // --- ctx: i-slice = tid>>5 (16 slices), float4 column = tid&31 ---
    int hq = tid & 31;
    int is = tid >> 5;
    float4 acc = {0.0f, 0.0f, 0.0f, 0.0f};
    const float4* ob = (const float4*)(out + b * Sn * Hn);
    for (int i = is; i <= t; i += 16) {
        float s = sc[i];
        float4 o4 = ob[i * (Hn / 4) + hq];
        acc.x += s * o4.x; acc.y += s * o4.y;
        acc.z += s * o4.z; acc.w += s * o4.w;
    }
    ((float4*)part[is])[hq] = acc;
    __syncthreads();
    if (tid < Hn) {
        float s2 = 0.0f;
#pragma unroll
        for (int r = 0; r < 16; r++) s2 += part[r][tid];
        oc[tid]      = os[tid];
        oc[tid + Hn] = s2 * inv;
    }
    __syncthreads();

    // --- fused final projection: logits = [out,ctx] @ Wf.T + bf ---
    int vo = tid & 127;   // vocab row
    int kq = tid >> 7;    // K-quarter of 256
    const float4* wr = (const float4*)(Wf + vo * 2 * Hn + kq * 64);
    const float*  ocq = oc + kq * 64;
    float facc = 0.0f;
#pragma unroll
    for (int i = 0; i < 16; i++) {
        float4 w4 = wr[i];
        facc += w4.x * ocq[4*i] + w4.y * ocq[4*i+1]
              + w4.z * ocq[4*i+2] + w4.w * ocq[4*i+3];
    }
    part[kq][vo] = facc;
    __syncthreads();
    if (tid < Vn) {
        logits[(b * Sn + t) * Vn + tid] =
            bf[tid] + part[0][tid] + part[1][tid] + part[2][tid] + part[3][tid];
    }
}

extern "C" void kernel_launch(void* const* d_in, const int* in_sizes, int n_in,
                              void* d_out, int out_size, void* d_ws, size_t ws_size,
                              hipStream_t stream) {
    const int*   x   = (const int*)d_in[0];
    const float* emb = (const float*)d_in[1];
    const float* Wih = (const float*)d_in[2];
    const float* Whh = (const float*)d_in[3];
    const float* bih = (const float*)d_in[4];
    const float* bhh = (const float*)d_in[5];
    const float* Wq  = (const float*)d_in[6];
    const float* bq  = (const float*)d_in[7];
    const float* Wk  = (const float*)d_in[8];
    const float* bk  = (const float*)d_in[9];
    const float* v   = (const float*)d_in[10];
    const float* Wf  = (const float*)d_in[11];
    const float* bf  = (const float*)d_in[12];

    float* logits = (float*)d_out;                 // (B,S,V) = 262144
    float* hT     = logits + Bn * Sn * Vn;         // (B,H)   = 512
    float* cT     = hT + Bn * Hn;                  // (B,H)   = 512

    float* ws   = (float*)d_ws;
    float* Gtab = ws;                               // V*4H   = 65536 floats
    float* outb = ws + 65536;                       // B*S*H  = 262144
    float* qo   = ws + 65536 + 262144;
    float* ko   = ws + 65536 + 2 * 262144;

    k_gtab<<<Vn, 512, 0, stream>>>(emb, Wih, bih, bhh, Gtab);
    k_lstm<<<Bn, 1024, 0, stream>>>(Whh, Gtab, x, outb, hT, cT);
    k_qk<<<Bn * Sn, 256, 0, stream>>>(outb, Wq, bq, Wk, bk, qo, ko);
    k_attn<<<Bn * Sn, 512, 0, stream>>>(qo, ko, v, outb, Wf, bf, logits);
}

// Round 8
// 680.157 us; speedup vs baseline: 2.1436x; 2.1436x over previous
//
#include <hip/hip_runtime.h>

#define Vn 128
#define En 32
#define Hn 128
#define Bn 4
#define Sn 512
#define G4H 512   // 4*Hn

typedef float f4 __attribute__((ext_vector_type(4)));

__device__ __forceinline__ float fsigmoid(float x) {
    return 1.0f / (1.0f + __expf(-x));
}

__device__ __forceinline__ float ftanh(float x) {
    float ax = fabsf(x);
    float e  = __expf(2.0f * ax);
    float t  = 1.0f - 2.0f / (e + 1.0f);
    return copysignf(t, x);
}

// Sum across the 4 lanes of each aligned lane-quad via DPP quad_perm.
__device__ __forceinline__ float quad_sum(float v) {
    v += __int_as_float(__builtin_amdgcn_update_dpp(
            0, __float_as_int(v), 0xB1, 0xF, 0xF, true));
    v += __int_as_float(__builtin_amdgcn_update_dpp(
            0, __float_as_int(v), 0x4E, 0xF, 0xF, true));
    return v;
}

// ---------------------------------------------------------------------------
// Kernel A: Gtab[v][j][g] = (b_ih+b_hh)[g*128+j] + emb[v]·W_ih[g*128+j]
// ---------------------------------------------------------------------------
__global__ __launch_bounds__(512) void k_gtab(
        const float* __restrict__ emb, const float* __restrict__ Wih,
        const float* __restrict__ bih, const float* __restrict__ bhh,
        float* __restrict__ Gtab) {
    int v  = blockIdx.x;
    int t  = threadIdx.x;
    int j  = t >> 2;
    int gt = t & 3;
    int r  = gt * Hn + j;
    __shared__ float e[En];
    if (t < En) e[t] = emb[v * En + t];
    __syncthreads();
    const float4* wr = (const float4*)(Wih + r * En);
    float acc = bih[r] + bhh[r];
#pragma unroll
    for (int i = 0; i < En / 4; i++) {
        float4 w4 = wr[i];
        acc += w4.x * e[4*i] + w4.y * e[4*i+1] + w4.z * e[4*i+2] + w4.w * e[4*i+3];
    }
    Gtab[v * G4H + t] = acc;   // [v][j][gt]
}

// ---------------------------------------------------------------------------
// Kernel B: LSTM recurrence. One block per batch (4 CUs), 512 threads.
// tid = 4j+q (within-wave): quad lanes q=0..3 hold 32-wide K-slices of row
// j's 4 gate dots; DPP quad butterfly completes them; activations in q==0.
//
// Residency (R1-R7 ledger): per-element asm pins do NOT force joint liveness
// (each value can materialize just before its own asm) -> VGPR stayed ~90 and
// V ALU stream bloated with copies (R5: 98% VALUBusy, 2230 cyc/step). Fix: ONE
// fat asm per iteration with all 32 float4s as "+v" operands -> all 128
// weight floats provably live at a single point each iteration, remat
// illegal, pressure ~190 < 256-reg budget at waves_per_eu(2,2).
// gfx950 note: v_fma_f32 cannot source AGPRs (R7 compile error) — weights
// must live in architectural VGPRs.
// ---------------------------------------------------------------------------
__global__ __attribute__((amdgpu_flat_work_group_size(512, 512),
                          amdgpu_waves_per_eu(2, 2)))
void k_lstm(
        const float* __restrict__ Whh, const float* __restrict__ Gtab,
        const int* __restrict__ x,
        float* __restrict__ out, float* __restrict__ hT, float* __restrict__ cT) {
    int b   = blockIdx.x;
    int tid = threadIdx.x;
    int wv  = tid >> 6;
    int ln  = tid & 63;
    int q   = ln & 3;                 // K-slice [32q, 32q+32)
    int j   = (wv << 4) | (ln >> 2);  // hidden index 0..127

    __shared__ float hbuf[2][144];        // 4 slices x 36-dword stride
    __shared__ float hstage[2][8][Hn];    // double-buffered octet stage
    __shared__ int   xb[Sn];

    xb[tid] = x[b * Sn + tid];
    if (tid < 288) ((float*)hbuf)[tid] = 0.0f;

    // weights: rows {g*128+j}, cols [32q,32q+32) -> w[g*8+i] = 32 float4
    f4 w[32];
#pragma unroll
    for (int g = 0; g < 4; g++) {
        const f4* row = (const f4*)(Whh + (g * Hn + j) * Hn + q * 32);
#pragma unroll
        for (int i = 0; i < 8; i++) w[g * 8 + i] = row[i];
    }

    float c = 0.0f, h = 0.0f;
    __syncthreads();

    float* out_base = out + b * Sn * Hn;

    for (int s = 0; s < Sn; s++) {
        // THE fat pin: all 32 quads live here, every iteration.
        asm volatile("" :
            "+v"(w[0]),  "+v"(w[1]),  "+v"(w[2]),  "+v"(w[3]),
            "+v"(w[4]),  "+v"(w[5]),  "+v"(w[6]),  "+v"(w[7]),
            "+v"(w[8]),  "+v"(w[9]),  "+v"(w[10]), "+v"(w[11]),
            "+v"(w[12]), "+v"(w[13]), "+v"(w[14]), "+v"(w[15]),
            "+v"(w[16]), "+v"(w[17]), "+v"(w[18]), "+v"(w[19]),
            "+v"(w[20]), "+v"(w[21]), "+v"(w[22]), "+v"(w[23]),
            "+v"(w[24]), "+v"(w[25]), "+v"(w[26]), "+v"(w[27]),
            "+v"(w[28]), "+v"(w[29]), "+v"(w[30]), "+v"(w[31]));

        // gate bias for this step (only q==0 lanes consume it)
        f4 gx = {0.f, 0.f, 0.f, 0.f};
        if (q == 0) gx = *(const f4*)(Gtab + xb[s] * G4H + j * 4);

        // h_{s-1} slice (stride-36: 4 distinct addrs/wave -> conflict-free,
        // 16-lane same-address groups broadcast)
        const f4* hp = (const f4*)(hbuf[(s + 1) & 1] + 36 * q);

        float p0 = 0.f, p1 = 0.f, p2 = 0.f, p3 = 0.f;
#pragma unroll
        for (int i = 0; i < 8; i++) {
            f4 hv = hp[i];
            p0 += w[i].x      * hv.x + w[i].y      * hv.y
                + w[i].z      * hv.z + w[i].w      * hv.w;
            p1 += w[8 + i].x  * hv.x + w[8 + i].y  * hv.y
                + w[8 + i].z  * hv.z + w[8 + i].w  * hv.w;
            p2 += w[16 + i].x * hv.x + w[16 + i].y * hv.y
                + w[16 + i].z * hv.z + w[16 + i].w * hv.w;
            p3 += w[24 + i].x * hv.x + w[24 + i].y * hv.y
                + w[24 + i].z * hv.z + w[24 + i].w * hv.w;
        }
        p0 = quad_sum(p0);
        p1 = quad_sum(p1);
        p2 = quad_sum(p2);
        p3 = quad_sum(p3);

        if (q == 0) {   // activations; (c,h) live in q==0 lanes
            float gi = gx.x + p0;
            float gf = gx.y + p1;
            float gg = gx.z + p2;
            float go = gx.w + p3;
            c = fsigmoid(gf) * c + fsigmoid(gi) * ftanh(gg);
            h = fsigmoid(go) * ftanh(c);
            hbuf[s & 1][36 * (j >> 5) + (j & 31)] = h;
            hstage[(s >> 3) & 1][s & 7][j] = h;
        }
        __syncthreads();

        if ((s & 7) == 7) {   // flush 8 steps of h, coalesced float2/lane
            const float2* src = (const float2*)hstage[(s >> 3) & 1];
            float2 v2 = src[tid];
            *(float2*)(out_base + (s - 7) * Hn + 2 * tid) = v2;
        }
    }
    if (q == 0) {
        hT[b * Hn + j] = h;
        cT[b * Hn + j] = c;
    }
}

// ---------------------------------------------------------------------------
// Kernel C: q = out@Wq.T + bq ; k = out@Wk.T + bk
// ---------------------------------------------------------------------------
__global__ __launch_bounds__(256) void k_qk(
        const float* __restrict__ out, const float* __restrict__ Wq,
        const float* __restrict__ bq, const float* __restrict__ Wk,
        const float* __restrict__ bk, float* __restrict__ qo, float* __restrict__ ko) {
    int bs  = blockIdx.x;
    int tid = threadIdx.x;
    __shared__ float o[Hn];
    if (tid < Hn) o[tid] = out[bs * Hn + tid];
    __syncthreads();
    int h = tid & 127;
    const float* Wm = (tid < Hn) ? Wq : Wk;
    const float* bm = (tid < Hn) ? bq : bk;
    const float4* wr = (const float4*)(Wm + h * Hn);
    float acc = bm[h];
#pragma unroll
    for (int i = 0; i < Hn / 4; i++) {
        float4 w4 = wr[i];
        acc += w4.x * o[4*i] + w4.y * o[4*i+1] + w4.z * o[4*i+2] + w4.w * o[4*i+3];
    }
    float* dst = (tid < Hn) ? qo : ko;
    dst[bs * Hn + h] = acc;
}

// ---------------------------------------------------------------------------
// Kernel D: Bahdanau scores + causal softmax + ctx + final projection fused.
// Block per (b,t), 512 threads. ctx never leaves LDS.
// ---------------------------------------------------------------------------
__global__ __launch_bounds__(512) void k_attn(
        const float* __restrict__ qo, const float* __restrict__ ko,
        const float* __restrict__ vvec, const float* __restrict__ out,
        const float* __restrict__ Wf, const float* __restrict__ bf,
        float* __restrict__ logits) {
    int b   = blockIdx.x >> 9;
    int t   = blockIdx.x & (Sn - 1);
    int tid = threadIdx.x;
    int ln  = tid & 63;
    int wv  = tid >> 6;
    __shared__ float qs[Hn];
    __shared__ float vs[Hn];
    __shared__ float os[Hn];
    __shared__ float sc[Sn];
    __shared__ float redm[8];
    __shared__ float reds[8];
    __shared__ float part[16][Hn];
    __shared__ float oc[2 * Hn];

    if (tid < Hn) {
        qs[tid] = qo[(b * Sn + t) * Hn + tid];
        vs[tid] = vvec[tid];
        os[tid] = out[(b * Sn + t) * Hn + tid];
    }
    __syncthreads();

    float sval = 0.0f;
    float a = -1e30f;
    if (tid <= t) {
        const float4* kr = (const float4*)(ko + (b * Sn + tid) * Hn);
        float s = 0.0f;
#pragma unroll
        for (int u = 0; u < Hn / 4; u++) {
            float4 k4 = kr[u];
            s += vs[4*u]   * ftanh(qs[4*u]   + k4.x);
            s += vs[4*u+1] * ftanh(qs[4*u+1] + k4.y);
            s += vs[4*u+2] * ftanh(qs[4*u+2] + k4.z);
            s += vs[4*u+3] * ftanh(qs[4*u+3] + k4.w);
        }
        sval = s;
        a = s;
    }
#pragma unroll
    for (int off = 32; off >= 1; off >>= 1)
        a = fmaxf(a, __shfl_xor(a, off));
    if (ln == 0) redm[wv] = a;
    __syncthreads();
    float m = redm[0];
#pragma unroll
    for (int r = 1; r < 8; r++) m = fmaxf(m, redm[r]);

    float ev = 0.0f;
    if (tid <= t) {
        ev = __expf(sval - m);
        sc[tid] = ev;
    }
    float ssum = ev;
#pragma unroll
    for (int off = 32; off >= 1; off >>= 1)
        ssum += __shfl_xor(ssum, off);
    if (ln == 0) reds[wv] = ssum;
    __syncthreads();
    float tot = 0.0f;
#pragma unroll
    for (int r = 0; r < 8; r++) tot += reds[r];
    float inv = 1.0f / tot;

    int hq = tid & 31;
    int is = tid >> 5;
    float4 acc = {0.0f, 0.0f, 0.0f, 0.0f};
    const float4* ob = (const float4*)(out + b * Sn * Hn);
    for (int i = is; i <= t; i += 16) {
        float s = sc[i];
        float4 o4 = ob[i * (Hn / 4) + hq];
        acc.x += s * o4.x; acc.y += s * o4.y;
        acc.z += s * o4.z; acc.w += s * o4.w;
    }
    ((float4*)part[is])[hq] = acc;
    __syncthreads();
    if (tid < Hn) {
        float s2 = 0.0f;
#pragma unroll
        for (int r = 0; r < 16; r++) s2 += part[r][tid];
        oc[tid]      = os[tid];
        oc[tid + Hn] = s2 * inv;
    }
    __syncthreads();

    int vo = tid & 127;
    int kq = tid >> 7;
    const float4* wr = (const float4*)(Wf + vo * 2 * Hn + kq * 64);
    const float*  ocq = oc + kq * 64;
    float facc = 0.0f;
#pragma unroll
    for (int i = 0; i < 16; i++) {
        float4 w4 = wr[i];
        facc += w4.x * ocq[4*i] + w4.y * ocq[4*i+1]
              + w4.z * ocq[4*i+2] + w4.w * ocq[4*i+3];
    }
    part[kq][vo] = facc;
    __syncthreads();
    if (tid < Vn) {
        logits[(b * Sn + t) * Vn + tid] =
            bf[tid] + part[0][tid] + part[1][tid] + part[2][tid] + part[3][tid];
    }
}

extern "C" void kernel_launch(void* const* d_in, const int* in_sizes, int n_in,
                              void* d_out, int out_size, void* d_ws, size_t ws_size,
                              hipStream_t stream) {
    const int*   x   = (const int*)d_in[0];
    const float* emb = (const float*)d_in[1];
    const float* Wih = (const float*)d_in[2];
    const float* Whh = (const float*)d_in[3];
    const float* bih = (const float*)d_in[4];
    const float* bhh = (const float*)d_in[5];
    const float* Wq  = (const float*)d_in[6];
    const float* bq  = (const float*)d_in[7];
    const float* Wk  = (const float*)d_in[8];
    const float* bk  = (const float*)d_in[9];
    const float* v   = (const float*)d_in[10];
    const float* Wf  = (const float*)d_in[11];
    const float* bf  = (const float*)d_in[12];

    float* logits = (float*)d_out;                 // (B,S,V) = 262144
    float* hT     = logits + Bn * Sn * Vn;         // (B,H)   = 512
    float* cT     = hT + Bn * Hn;                  // (B,H)   = 512

    float* ws   = (float*)d_ws;
    float* Gtab = ws;                               // V*4H   = 65536 floats
    float* outb = ws + 65536;                       // B*S*H  = 262144
    float* qo   = ws + 65536 + 262144;
    float* ko   = ws + 65536 + 2 * 262144;

    k_gtab<<<Vn, 512, 0, stream>>>(emb, Wih, bih, bhh, Gtab);
    k_lstm<<<Bn, 512, 0, stream>>>(Whh, Gtab, x, outb, hT, cT);
    k_qk<<<Bn * Sn, 256, 0, stream>>>(outb, Wq, bq, Wk, bk, qo, ko);
    k_attn<<<Bn * Sn, 512, 0, stream>>>(qo, ko, v, outb, Wf, bf, logits);
}